// Round 5
// baseline (453.672 us; speedup 1.0000x reference)
//
#include <hip/hip_runtime.h>

typedef __attribute__((ext_vector_type(8))) short bf16x8;
typedef __attribute__((ext_vector_type(4))) float f32x4;

#define MFMA16(a,b,c) __builtin_amdgcn_mfma_f32_16x16x32_bf16((a),(b),(c),0,0,0)

#define AS1 __attribute__((address_space(1)))
#define AS3 __attribute__((address_space(3)))
__device__ __forceinline__ void async16(void* lds, const void* g){
  __builtin_amdgcn_global_load_lds((const AS1 unsigned int*)g, (AS3 unsigned int*)lds, 16, 0, 0);
}

__device__ __forceinline__ unsigned short f2bf(float f){
  unsigned int u = __float_as_uint(f);
  unsigned int r = (u + 0x7fffu + ((u>>16)&1u)) >> 16;
  return (unsigned short)r;
}
__device__ __forceinline__ float bf2f(unsigned short h){
  return __uint_as_float(((unsigned int)h)<<16);
}
__device__ __forceinline__ float tanh_fast(float x){
  float e = __expf(2.f*x);
  return 1.f - 2.f/(e + 1.f);
}

// ---- workspace byte offsets ----
#define WS_W1H   0u           // [4 mt][8 kt][64 lane][8] bf16 hi  (32768 B)
#define WS_W1L   32768u
#define WS_WHHH  65536u       // [3][16 nt][8 kt][64][8] bf16 hi   (393216 B)
#define WS_WHHL  458752u
#define WS_Y1    851968u      // [640][64][10][10] f32             (16384000 B)
#define WS_Y2    17235968u    // [640][3] f32
#define WS_LAST  17255936u    // [3][16][256] f32

// ================= prep: split W1 / Whh into MFMA fragment layout =================
__global__ __launch_bounds__(256) void k_prep(const float* __restrict__ W1,
                                              const float* __restrict__ Whh,
                                              unsigned short* __restrict__ w1h,
                                              unsigned short* __restrict__ w1l,
                                              unsigned short* __restrict__ whh_h,
                                              unsigned short* __restrict__ whh_l){
  int t = blockIdx.x*256 + threadIdx.x;
  if (t < 2048){
    int l = t & 63, kt = (t>>6)&7, mt = t>>9;
    int co = mt*16 + (l&15);
    int k0 = kt*32 + ((l>>4)<<3);
    bf16x8 hv, lv;
    #pragma unroll
    for (int j=0;j<8;j++){
      int k = k0 + j;
      float v = (k < 243) ? W1[co*243 + k] : 0.f;
      unsigned short h = f2bf(v);
      unsigned short lo = f2bf(v - bf2f(h));
      hv[j] = (short)h; lv[j] = (short)lo;
    }
    *(bf16x8*)(w1h + (size_t)t*8) = hv;
    *(bf16x8*)(w1l + (size_t)t*8) = lv;
  } else if (t < 2048 + 24576){
    int u = t - 2048;
    int l = u & 63, kt = (u>>6)&7, nt = (u>>9)&15, rnn = u>>13;
    int o = nt*16 + (l&15);
    int k0 = kt*32 + ((l>>4)<<3);
    const float* src = Whh + ((size_t)rnn*256 + o)*256;
    bf16x8 hv, lv;
    #pragma unroll
    for (int j=0;j<8;j++){
      float v = src[k0 + j];
      unsigned short h = f2bf(v);
      unsigned short lo = f2bf(v - bf2f(h));
      hv[j] = (short)h; lv[j] = (short)lo;
    }
    *(bf16x8*)(whh_h + (size_t)u*8) = hv;
    *(bf16x8*)(whh_l + (size_t)u*8) = lv;
  }
}

// ================= conv1 (9x9 stride 9) + bias + relu + 2x2 maxpool =================
// block = (frame, oy-pair g); rows 2g,2g+1 processed SEQUENTIALLY in the same 20-patch
// B-planes. LDS = 20480 B -> 8 blocks/CU (100% occupancy). Pooling in registers via
// shfl_xor pair-max (ALL lanes execute shuffles; only the store is predicated).
__global__ __launch_bounds__(256,8) void k_conv1(const float* __restrict__ x,
                                                 const float* __restrict__ b1,
                                                 const unsigned short* __restrict__ w1h,
                                                 const unsigned short* __restrict__ w1l,
                                                 float* __restrict__ y1){
  __shared__ __align__(16) char smem[20480];   // hi[20][256]bf16 @0, lo @10240, XOR-swizzled
  int fr = blockIdx.x/10, g = blockIdx.x%10;
  int t = threadIdx.x, w = t>>6, l = t&63;

  // A = W1 fragments (split), one co-tile per wave
  bf16x8 ah[8], al[8];
  #pragma unroll
  for (int kt=0;kt<8;kt++){
    size_t fi = (((size_t)(w*8+kt))*64 + l)*8;
    ah[kt] = *(const bf16x8*)(w1h+fi);
    al[kt] = *(const bf16x8*)(w1l+fi);
  }
  float bias[4];
  #pragma unroll
  for (int reg=0;reg<4;reg++) bias[reg] = b1[w*16 + ((l>>4)<<2) + reg];

  const float4* xb = (const float4*)x + (size_t)fr*24300;
  int rowbase = g*18;

  // per-thread scatter mapping (identical for both rows)
  float4 rv[5]; int pp[5], kk[5], kxv[5]; bool okv[5];
  #pragma unroll
  for (int ii=0; ii<5; ii++){
    int i = t + (ii<<8);
    okv[ii] = (i < 1215);
    int c = i/405, rem = i - c*405;
    int ky = rem/45, quad = rem - ky*45;
    int col0 = quad<<2;
    int ox = (col0*57)>>9;           // floor(col0/9) for col0<180
    kxv[ii] = col0 - 9*ox;
    pp[ii] = ox;
    kk[ii] = c*81 + ky*9;
    int gi = c*8100 + (rowbase + ky)*45 + quad;
    rv[ii] = okv[ii] ? xb[gi] : (float4){0.f,0.f,0.f,0.f};   // row A loads in flight
  }
  // zero pad k in [243,256) once; persists across both rows
  for (int i=t; i<260; i+=256){
    int p = i/13, k = 243 + (i - p*13);
    int off = ((p<<9)+(k<<1)) ^ ((p&7)<<4);
    *(unsigned short*)(smem+off) = 0;
    *(unsigned short*)(smem+10240+off) = 0;
  }
  // scatter row A (waits on rv here)
  #pragma unroll
  for (int ii=0; ii<5; ii++){
    if (okv[ii]){
      int p = pp[ii], kx = kxv[ii];
      float vv[4] = {rv[ii].x, rv[ii].y, rv[ii].z, rv[ii].w};
      #pragma unroll
      for (int q=0;q<4;q++){
        int k = kk[ii] + kx;
        int off = ((p<<9)+(k<<1)) ^ ((p&7)<<4);
        unsigned int u = __float_as_uint(vv[q]);
        *(unsigned short*)(smem+off) = (unsigned short)(u>>16);
        float lof = vv[q] - __uint_as_float(u & 0xffff0000u);
        *(unsigned short*)(smem+10240+off) = (unsigned short)(__float_as_uint(lof)>>16);
        kx++; if (kx==9){ kx=0; p++; }
      }
    }
  }
  __syncthreads();

  // issue row B loads NOW — they fly under row A's MFMA phase
  #pragma unroll
  for (int ii=0; ii<5; ii++){
    int i = t + (ii<<8);
    int c = i/405, rem = i - c*405;
    int ky = rem/45, quad = rem - ky*45;
    int gi = c*8100 + (rowbase + 9 + ky)*45 + quad;
    rv[ii] = okv[ii] ? xb[gi] : (float4){0.f,0.f,0.f,0.f};
  }

  // MFMA row A: n-tiles at patches {0..15} and {4..19}
  int m = l&15, colb = (l>>4)<<4;
  int p0 = m, p1 = 4+m;
  int sw0 = (p0&7)<<4, sw1 = (p1&7)<<4;
  f32x4 acc0 = (f32x4){0.f,0.f,0.f,0.f}, acc1 = acc0;
  #pragma unroll
  for (int kt=0;kt<8;kt++){
    int off0 = ((p0<<9)+(kt<<6)+colb) ^ sw0;
    int off1 = ((p1<<9)+(kt<<6)+colb) ^ sw1;
    bf16x8 bh0 = *(const bf16x8*)(smem+off0);
    bf16x8 bl0 = *(const bf16x8*)(smem+10240+off0);
    bf16x8 bh1 = *(const bf16x8*)(smem+off1);
    bf16x8 bl1 = *(const bf16x8*)(smem+10240+off1);
    acc0 = MFMA16(ah[kt], bh0, acc0);
    acc0 = MFMA16(ah[kt], bl0, acc0);
    acc0 = MFMA16(al[kt], bh0, acc0);
    acc1 = MFMA16(ah[kt], bh1, acc1);
    acc1 = MFMA16(ah[kt], bl1, acc1);
    acc1 = MFMA16(al[kt], bh1, acc1);
  }
  // pool row A horizontally into registers (all lanes, uniform shuffles)
  float vA0[4], vA1[4];
  #pragma unroll
  for (int reg=0;reg<4;reg++){
    float v0 = fmaxf(acc0[reg]+bias[reg], 0.f);
    vA0[reg] = fmaxf(v0, __shfl_xor(v0,1));
    float v1 = fmaxf(acc1[reg]+bias[reg], 0.f);
    vA1[reg] = fmaxf(v1, __shfl_xor(v1,1));
  }
  __syncthreads();   // all waves done reading row-A planes

  // scatter row B
  #pragma unroll
  for (int ii=0; ii<5; ii++){
    if (okv[ii]){
      int p = pp[ii], kx = kxv[ii];
      float vv[4] = {rv[ii].x, rv[ii].y, rv[ii].z, rv[ii].w};
      #pragma unroll
      for (int q=0;q<4;q++){
        int k = kk[ii] + kx;
        int off = ((p<<9)+(k<<1)) ^ ((p&7)<<4);
        unsigned int u = __float_as_uint(vv[q]);
        *(unsigned short*)(smem+off) = (unsigned short)(u>>16);
        float lof = vv[q] - __uint_as_float(u & 0xffff0000u);
        *(unsigned short*)(smem+10240+off) = (unsigned short)(__float_as_uint(lof)>>16);
        kx++; if (kx==9){ kx=0; p++; }
      }
    }
  }
  __syncthreads();

  // MFMA row B
  acc0 = (f32x4){0.f,0.f,0.f,0.f}; acc1 = acc0;
  #pragma unroll
  for (int kt=0;kt<8;kt++){
    int off0 = ((p0<<9)+(kt<<6)+colb) ^ sw0;
    int off1 = ((p1<<9)+(kt<<6)+colb) ^ sw1;
    bf16x8 bh0 = *(const bf16x8*)(smem+off0);
    bf16x8 bl0 = *(const bf16x8*)(smem+10240+off0);
    bf16x8 bh1 = *(const bf16x8*)(smem+off1);
    bf16x8 bl1 = *(const bf16x8*)(smem+10240+off1);
    acc0 = MFMA16(ah[kt], bh0, acc0);
    acc0 = MFMA16(ah[kt], bl0, acc0);
    acc0 = MFMA16(al[kt], bh0, acc0);
    acc1 = MFMA16(ah[kt], bh1, acc1);
    acc1 = MFMA16(ah[kt], bl1, acc1);
    acc1 = MFMA16(al[kt], bh1, acc1);
  }
  // pool row B + combine with row A — ALL lanes execute the shuffles; store predicated
  size_t ybase = (size_t)fr*6400 + g*10;
  #pragma unroll
  for (int reg=0;reg<4;reg++){
    int co = w*16 + ((l>>4)<<2) + reg;
    float v0 = fmaxf(acc0[reg]+bias[reg], 0.f);
    v0 = fmaxf(v0, __shfl_xor(v0,1));
    float r0 = fmaxf(vA0[reg], v0);
    float v1 = fmaxf(acc1[reg]+bias[reg], 0.f);
    v1 = fmaxf(v1, __shfl_xor(v1,1));
    float r1 = fmaxf(vA1[reg], v1);
    if ((m&1)==0){
      y1[ybase + co*100 + (m>>1)] = r0;
      if (m >= 12)
        y1[ybase + co*100 + ((4+m)>>1)] = r1;
    }
  }
}

// ================= conv2 (5x5 stride 5) + bias + relu + 2x2 maxpool -> y[640][3] =================
__global__ __launch_bounds__(256) void k_conv2(const float* __restrict__ y1,
                                               const float* __restrict__ W2,
                                               const float* __restrict__ b2,
                                               float* __restrict__ y2){
  __shared__ __align__(16) float yl[6400];
  __shared__ __align__(16) float w2s[4800];
  int fr = blockIdx.x, t = threadIdx.x;
  const float4* src = (const float4*)(y1 + (size_t)fr*6400);
  for (int i=t;i<1600;i+=256) async16(((float4*)yl) + i, (const void*)(src + i));
  for (int i=t;i<1200;i+=256) async16(((float4*)w2s) + i, (const void*)(((const float4*)W2) + i));
  __syncthreads();
  if (t < 192){
    int o = t>>4, l16 = t&15;
    int ch = o>>2, pos = o&3;
    int oy = pos>>1, ox = pos&1;
    float s = 0.f;
    for (int i=0;i<100;i++){
      int k = l16 + (i<<4);
      int ci = k/25; int r = k - ci*25; int ky = r/5, kx = r - ky*5;
      s += yl[ci*100 + (5*oy+ky)*10 + 5*ox + kx] * w2s[ch*1600 + k];
    }
    #pragma unroll
    for (int d=1; d<16; d<<=1) s += __shfl_xor(s, d);
    float v = fmaxf(s + b2[ch], 0.f);
    v = fmaxf(v, __shfl_xor(v, 16));
    v = fmaxf(v, __shfl_xor(v, 32));
    if ((t&63)==0) y2[fr*3 + (t>>6)] = v;
  }
}

// ================= fused BN(train)+sort + 3 RNNs (one block per RNN) =================
__global__ __launch_bounds__(512) void k_rnn(const unsigned short* __restrict__ whh_h,
                                             const unsigned short* __restrict__ whh_l,
                                             const float* __restrict__ y2,
                                             const float* __restrict__ gamma,
                                             const float* __restrict__ beta,
                                             const float* __restrict__ Wih,
                                             const float* __restrict__ bih,
                                             const float* __restrict__ bhh,
                                             float* __restrict__ lasts){
  __shared__ __align__(16) char hsm[36864];  // buf0 @0 (hi|lo 8K+8K), buf1 @16384, seqL @32768
  float* yl   = (float*)hsm;                 // [1920] overlaid in buf0 during phase A
  float* af   = (float*)(hsm + 7680);        // [64]
  float* bfv  = (float*)(hsm + 7936);        // [64]
  float* rngL = (float*)(hsm + 8192);        // [10][3]
  int*   perm = (int*)(hsm + 8320);          // [10][3]
  float* tsb  = (float*)(hsm + 8448);        // [10][3][64]
  float* seqL = (float*)(hsm + 32768);       // [64][16]
  int rnn = blockIdx.x;
  int t = threadIdx.x, w = t>>6, l = t&63;

  bf16x8 Bh[2][8], Bl[2][8];                 // wave w owns n-tiles 2w, 2w+1
  #pragma unroll
  for (int q=0;q<2;q++){
    int nt = 2*w + q;
    #pragma unroll
    for (int kt=0;kt<8;kt++){
      size_t fi = (((((size_t)rnn*16 + nt)*8) + kt)*64 + l)*8;
      Bh[q][kt] = *(const bf16x8*)(whh_h + fi);
      Bl[q][kt] = *(const bf16x8*)(whh_l + fi);
    }
  }
  int o0 = (2*w)*16 + (l&15), o1 = o0 + 16;
  float wih0 = Wih[rnn*256 + o0], wih1 = Wih[rnn*256 + o1];
  float bs0 = bih[rnn*256+o0] + bhh[rnn*256+o0];
  float bs1 = bih[rnn*256+o1] + bhh[rnn*256+o1];

  // ---- phase A: BN + sort + seq build ----
  for (int i=t;i<1920;i+=512) yl[i] = y2[i];
  __syncthreads();
  if (t < 64){
    float mu = 0.f;
    for (int b=0;b<10;b++)
      for (int ch=0;ch<3;ch++) mu += yl[(b*64 + t)*3 + ch];
    mu *= (1.f/30.f);
    float v = 0.f;
    for (int b=0;b<10;b++)
      for (int ch=0;ch<3;ch++){ float d = yl[(b*64+t)*3+ch] - mu; v += d*d; }
    v *= (1.f/30.f);
    float rs = rsqrtf(v + 1e-5f);
    float a = gamma[t]*rs;
    af[t] = a; bfv[t] = beta[t] - mu*a;
  }
  __syncthreads();
  if (t < 30){
    int b = t/3, ch = t - b*3;
    float mx = -1e30f, mn = 1e30f;
    for (int f=0; f<64; f++){
      float v = yl[(b*64+f)*3+ch]*af[f] + bfv[f];
      tsb[(b*3+ch)*64 + f] = v;
      mx = fmaxf(mx, v); mn = fminf(mn, v);
    }
    rngL[b*3+ch] = mx - mn;
  }
  __syncthreads();
  if (t < 10){
    #pragma unroll
    for (int ch=0; ch<3; ch++){
      float rc = rngL[t*3+ch];
      int rank = 0;
      #pragma unroll
      for (int c2=0; c2<3; c2++){
        float r2 = rngL[t*3+c2];
        if (r2 < rc || (r2 == rc && c2 < ch)) rank++;   // stable argsort ascending
      }
      perm[t*3+rank] = ch;
    }
  }
  __syncthreads();
  for (int i=t;i<1024;i+=512){
    int step = i>>4, b = i&15;
    float v = 0.f;
    if (b < 10){ int p = perm[b*3 + rnn]; v = tsb[(b*3+p)*64 + step]; }
    seqL[i] = v;
  }
  __syncthreads();

  // ---- phase B: recurrence ----
  float4 z4 = {0.f,0.f,0.f,0.f};
  for (int i=t; i<1024; i+=512) ((float4*)hsm)[i] = z4;   // zero buf0 (h=0)
  __syncthreads();
  int arow = l&15, colb = (l>>4)<<4, sw = (arow&7)<<4;
  int b_base = (l>>4)<<2;
  for (int step=0; step<64; step++){
    char* cur = hsm + ((step&1)<<14);
    char* nxt = hsm + (((step+1)&1)<<14);
    f32x4 p0=(f32x4){0,0,0,0}, q0=p0, r0=p0, p1=p0, q1=p0, r1=p0;
    #pragma unroll
    for (int kt=0; kt<8; kt++){
      int off = ((arow<<9) + (kt<<6) + colb) ^ sw;
      bf16x8 ahv = *(const bf16x8*)(cur + off);
      bf16x8 alv = *(const bf16x8*)(cur + 8192 + off);
      p0 = MFMA16(ahv, Bh[0][kt], p0);
      q0 = MFMA16(ahv, Bl[0][kt], q0);
      r0 = MFMA16(alv, Bh[0][kt], r0);
      p1 = MFMA16(ahv, Bh[1][kt], p1);
      q1 = MFMA16(ahv, Bl[1][kt], q1);
      r1 = MFMA16(alv, Bh[1][kt], r1);
    }
    float4 sx = *(const float4*)(seqL + (step<<4) + b_base);
    float sxa[4] = {sx.x, sx.y, sx.z, sx.w};
    #pragma unroll
    for (int reg=0; reg<4; reg++){
      int b = b_base + reg;
      float a0 = (p0[reg] + q0[reg]) + r0[reg];
      float a1 = (p1[reg] + q1[reg]) + r1[reg];
      float h0 = tanh_fast(a0 + sxa[reg]*wih0 + bs0);
      float h1 = tanh_fast(a1 + sxa[reg]*wih1 + bs1);
      int wsw = (b&7)<<4;
      int off0 = ((b<<9) + (o0<<1)) ^ wsw;
      int off1 = ((b<<9) + (o1<<1)) ^ wsw;
      unsigned int u0 = __float_as_uint(h0);
      unsigned int u1 = __float_as_uint(h1);
      *(unsigned short*)(nxt + off0) = (unsigned short)(u0>>16);
      float l0 = h0 - __uint_as_float(u0 & 0xffff0000u);
      *(unsigned short*)(nxt + 8192 + off0) = (unsigned short)(__float_as_uint(l0)>>16);
      *(unsigned short*)(nxt + off1) = (unsigned short)(u1>>16);
      float l1 = h1 - __uint_as_float(u1 & 0xffff0000u);
      *(unsigned short*)(nxt + 8192 + off1) = (unsigned short)(__float_as_uint(l1)>>16);
      if (step == 63){
        lasts[((size_t)rnn*16 + b)*256 + o0] = h0;
        lasts[((size_t)rnn*16 + b)*256 + o1] = h1;
      }
    }
    __syncthreads();
  }
}

// ================= head: avg over 3 RNNs, @ Wl^T + bl -> out[10][5] =================
__global__ __launch_bounds__(512) void k_head(const float* __restrict__ lasts,
                                              const float* __restrict__ Wl,
                                              const float* __restrict__ bl,
                                              float* __restrict__ out){
  int t = threadIdx.x;
  if (t < 400){
    int oidx = t>>3, l8 = t&7;       // 50 outputs x 8 lanes
    int b = oidx/5, c = oidx - b*5;
    float s = 0.f;
    for (int i=0;i<32;i++){
      int o = (l8<<5) + i;
      float avg = (lasts[(size_t)(0*16+b)*256+o] + lasts[(size_t)(1*16+b)*256+o]
                 + lasts[(size_t)(2*16+b)*256+o]) * (1.f/3.f);
      s += avg * Wl[c*256 + o];
    }
    #pragma unroll
    for (int d=1; d<8; d<<=1) s += __shfl_xor(s, d);
    if (l8 == 0) out[oidx] = s + bl[c];
  }
}

extern "C" void kernel_launch(void* const* d_in, const int* in_sizes, int n_in,
                              void* d_out, int out_size, void* d_ws, size_t ws_size,
                              hipStream_t stream){
  const float* x    = (const float*)d_in[0];
  const float* W1   = (const float*)d_in[1];
  const float* b1   = (const float*)d_in[2];
  const float* W2   = (const float*)d_in[3];
  const float* b2   = (const float*)d_in[4];
  const float* gamma= (const float*)d_in[5];
  const float* beta = (const float*)d_in[6];
  const float* Wih  = (const float*)d_in[7];
  const float* Whh  = (const float*)d_in[8];
  const float* bih  = (const float*)d_in[9];
  const float* bhh  = (const float*)d_in[10];
  const float* Wl   = (const float*)d_in[11];
  const float* bl   = (const float*)d_in[12];
  char* ws = (char*)d_ws;
  unsigned short* w1h  = (unsigned short*)(ws + WS_W1H);
  unsigned short* w1l  = (unsigned short*)(ws + WS_W1L);
  unsigned short* whhh = (unsigned short*)(ws + WS_WHHH);
  unsigned short* whhl = (unsigned short*)(ws + WS_WHHL);
  float* y1   = (float*)(ws + WS_Y1);
  float* y2   = (float*)(ws + WS_Y2);
  float* last = (float*)(ws + WS_LAST);

  hipLaunchKernelGGL(k_prep,  dim3(104),  dim3(256), 0, stream, W1, Whh, w1h, w1l, whhh, whhl);
  hipLaunchKernelGGL(k_conv1, dim3(6400), dim3(256), 0, stream, x, b1, w1h, w1l, y1);
  hipLaunchKernelGGL(k_conv2, dim3(640),  dim3(256), 0, stream, y1, W2, b2, y2);
  hipLaunchKernelGGL(k_rnn,   dim3(3),    dim3(512), 0, stream, whhh, whhl, y2, gamma, beta, Wih, bih, bhh, last);
  hipLaunchKernelGGL(k_head,  dim3(1),    dim3(512), 0, stream, last, Wl, bl, (float*)d_out);
}

// Round 6
// 305.405 us; speedup vs baseline: 1.4855x; 1.4855x over previous
//
#include <hip/hip_runtime.h>

typedef __attribute__((ext_vector_type(8))) short bf16x8;
typedef __attribute__((ext_vector_type(4))) float f32x4;

#define MFMA16(a,b,c) __builtin_amdgcn_mfma_f32_16x16x32_bf16((a),(b),(c),0,0,0)

#define AS1 __attribute__((address_space(1)))
#define AS3 __attribute__((address_space(3)))
__device__ __forceinline__ void async16(void* lds, const void* g){
  __builtin_amdgcn_global_load_lds((const AS1 unsigned int*)g, (AS3 unsigned int*)lds, 16, 0, 0);
}

__device__ __forceinline__ unsigned short f2bf(float f){
  unsigned int u = __float_as_uint(f);
  unsigned int r = (u + 0x7fffu + ((u>>16)&1u)) >> 16;
  return (unsigned short)r;
}
__device__ __forceinline__ float bf2f(unsigned short h){
  return __uint_as_float(((unsigned int)h)<<16);
}
__device__ __forceinline__ float tanh_fast(float x){
  float e = __expf(2.f*x);
  return 1.f - 2.f/(e + 1.f);
}

// ---- workspace byte offsets ----
#define WS_W1H   0u           // [4 mt][8 kt][64 lane][8] bf16 hi  (32768 B)
#define WS_W1L   32768u
#define WS_WHHH  65536u       // [3][16 nt][8 kt][64][8] bf16 hi   (393216 B)
#define WS_WHHL  458752u
#define WS_Y1    851968u      // [640][64][10][10] f32             (16384000 B)
#define WS_Y2    17235968u    // [640][3] f32
#define WS_LAST  17255936u    // [3][16][256] f32

// ================= prep: split W1 / Whh into MFMA fragment layout =================
__global__ __launch_bounds__(256) void k_prep(const float* __restrict__ W1,
                                              const float* __restrict__ Whh,
                                              unsigned short* __restrict__ w1h,
                                              unsigned short* __restrict__ w1l,
                                              unsigned short* __restrict__ whh_h,
                                              unsigned short* __restrict__ whh_l){
  int t = blockIdx.x*256 + threadIdx.x;
  if (t < 2048){
    int l = t & 63, kt = (t>>6)&7, mt = t>>9;
    int co = mt*16 + (l&15);
    int k0 = kt*32 + ((l>>4)<<3);
    bf16x8 hv, lv;
    #pragma unroll
    for (int j=0;j<8;j++){
      int k = k0 + j;
      float v = (k < 243) ? W1[co*243 + k] : 0.f;
      unsigned short h = f2bf(v);
      unsigned short lo = f2bf(v - bf2f(h));
      hv[j] = (short)h; lv[j] = (short)lo;
    }
    *(bf16x8*)(w1h + (size_t)t*8) = hv;
    *(bf16x8*)(w1l + (size_t)t*8) = lv;
  } else if (t < 2048 + 24576){
    int u = t - 2048;
    int l = u & 63, kt = (u>>6)&7, nt = (u>>9)&15, rnn = u>>13;
    int o = nt*16 + (l&15);
    int k0 = kt*32 + ((l>>4)<<3);
    const float* src = Whh + ((size_t)rnn*256 + o)*256;
    bf16x8 hv, lv;
    #pragma unroll
    for (int j=0;j<8;j++){
      float v = src[k0 + j];
      unsigned short h = f2bf(v);
      unsigned short lo = f2bf(v - bf2f(h));
      hv[j] = (short)h; lv[j] = (short)lo;
    }
    *(bf16x8*)(whh_h + (size_t)u*8) = hv;
    *(bf16x8*)(whh_l + (size_t)u*8) = lv;
  }
}

// ================= conv1 (9x9 stride 9) + bias + relu + 2x2 maxpool =================
// block = (frame, oy-pair g); rows 2g,2g+1 processed SEQUENTIALLY in the same 20-patch
// B-planes. LDS = 20480 B. __launch_bounds__(256,4): 128-VGPR cap — NO SPILLS (round 5's
// (256,8) forced a 32-VGPR allocation and 1.3 GB of scratch traffic). Pooling in
// registers via shfl_xor pair-max (all lanes shuffle; only stores predicated).
__global__ __launch_bounds__(256,4) void k_conv1(const float* __restrict__ x,
                                                 const float* __restrict__ b1,
                                                 const unsigned short* __restrict__ w1h,
                                                 const unsigned short* __restrict__ w1l,
                                                 float* __restrict__ y1){
  __shared__ __align__(16) char smem[20480];   // hi[20][256]bf16 @0, lo @10240, XOR-swizzled
  int fr = blockIdx.x/10, g = blockIdx.x%10;
  int t = threadIdx.x, w = t>>6, l = t&63;

  // A = W1 fragments (split), one co-tile per wave
  bf16x8 ah[8], al[8];
  #pragma unroll
  for (int kt=0;kt<8;kt++){
    size_t fi = (((size_t)(w*8+kt))*64 + l)*8;
    ah[kt] = *(const bf16x8*)(w1h+fi);
    al[kt] = *(const bf16x8*)(w1l+fi);
  }
  float bias[4];
  #pragma unroll
  for (int reg=0;reg<4;reg++) bias[reg] = b1[w*16 + ((l>>4)<<2) + reg];

  const float4* xb = (const float4*)x + (size_t)fr*24300;
  int rowbase = g*18;

  // per-thread scatter mapping (identical for both rows)
  float4 rv[5]; int pp[5], kk[5], kxv[5]; bool okv[5];
  #pragma unroll
  for (int ii=0; ii<5; ii++){
    int i = t + (ii<<8);
    okv[ii] = (i < 1215);
    int c = i/405, rem = i - c*405;
    int ky = rem/45, quad = rem - ky*45;
    int col0 = quad<<2;
    int ox = (col0*57)>>9;           // floor(col0/9) for col0<180
    kxv[ii] = col0 - 9*ox;
    pp[ii] = ox;
    kk[ii] = c*81 + ky*9;
    int gi = c*8100 + (rowbase + ky)*45 + quad;
    rv[ii] = okv[ii] ? xb[gi] : (float4){0.f,0.f,0.f,0.f};   // row A loads in flight
  }
  // zero pad k in [243,256) once; persists across both rows
  for (int i=t; i<260; i+=256){
    int p = i/13, k = 243 + (i - p*13);
    int off = ((p<<9)+(k<<1)) ^ ((p&7)<<4);
    *(unsigned short*)(smem+off) = 0;
    *(unsigned short*)(smem+10240+off) = 0;
  }
  // scatter row A (waits on rv here)
  #pragma unroll
  for (int ii=0; ii<5; ii++){
    if (okv[ii]){
      int p = pp[ii], kx = kxv[ii];
      float vv[4] = {rv[ii].x, rv[ii].y, rv[ii].z, rv[ii].w};
      #pragma unroll
      for (int q=0;q<4;q++){
        int k = kk[ii] + kx;
        int off = ((p<<9)+(k<<1)) ^ ((p&7)<<4);
        unsigned int u = __float_as_uint(vv[q]);
        *(unsigned short*)(smem+off) = (unsigned short)(u>>16);
        float lof = vv[q] - __uint_as_float(u & 0xffff0000u);
        *(unsigned short*)(smem+10240+off) = (unsigned short)(__float_as_uint(lof)>>16);
        kx++; if (kx==9){ kx=0; p++; }
      }
    }
  }
  __syncthreads();

  // issue row B loads NOW — they fly under row A's MFMA phase
  #pragma unroll
  for (int ii=0; ii<5; ii++){
    int i = t + (ii<<8);
    int c = i/405, rem = i - c*405;
    int ky = rem/45, quad = rem - ky*45;
    int gi = c*8100 + (rowbase + 9 + ky)*45 + quad;
    rv[ii] = okv[ii] ? xb[gi] : (float4){0.f,0.f,0.f,0.f};
  }

  // MFMA row A: n-tiles at patches {0..15} and {4..19}
  int m = l&15, colb = (l>>4)<<4;
  int p0 = m, p1 = 4+m;
  int sw0 = (p0&7)<<4, sw1 = (p1&7)<<4;
  f32x4 acc0 = (f32x4){0.f,0.f,0.f,0.f}, acc1 = acc0;
  #pragma unroll
  for (int kt=0;kt<8;kt++){
    int off0 = ((p0<<9)+(kt<<6)+colb) ^ sw0;
    int off1 = ((p1<<9)+(kt<<6)+colb) ^ sw1;
    bf16x8 bh0 = *(const bf16x8*)(smem+off0);
    bf16x8 bl0 = *(const bf16x8*)(smem+10240+off0);
    bf16x8 bh1 = *(const bf16x8*)(smem+off1);
    bf16x8 bl1 = *(const bf16x8*)(smem+10240+off1);
    acc0 = MFMA16(ah[kt], bh0, acc0);
    acc0 = MFMA16(ah[kt], bl0, acc0);
    acc0 = MFMA16(al[kt], bh0, acc0);
    acc1 = MFMA16(ah[kt], bh1, acc1);
    acc1 = MFMA16(ah[kt], bl1, acc1);
    acc1 = MFMA16(al[kt], bh1, acc1);
  }
  // pool row A horizontally into registers (all lanes, uniform shuffles)
  float vA0[4], vA1[4];
  #pragma unroll
  for (int reg=0;reg<4;reg++){
    float v0 = fmaxf(acc0[reg]+bias[reg], 0.f);
    vA0[reg] = fmaxf(v0, __shfl_xor(v0,1));
    float v1 = fmaxf(acc1[reg]+bias[reg], 0.f);
    vA1[reg] = fmaxf(v1, __shfl_xor(v1,1));
  }
  __syncthreads();   // all waves done reading row-A planes

  // scatter row B
  #pragma unroll
  for (int ii=0; ii<5; ii++){
    if (okv[ii]){
      int p = pp[ii], kx = kxv[ii];
      float vv[4] = {rv[ii].x, rv[ii].y, rv[ii].z, rv[ii].w};
      #pragma unroll
      for (int q=0;q<4;q++){
        int k = kk[ii] + kx;
        int off = ((p<<9)+(k<<1)) ^ ((p&7)<<4);
        unsigned int u = __float_as_uint(vv[q]);
        *(unsigned short*)(smem+off) = (unsigned short)(u>>16);
        float lof = vv[q] - __uint_as_float(u & 0xffff0000u);
        *(unsigned short*)(smem+10240+off) = (unsigned short)(__float_as_uint(lof)>>16);
        kx++; if (kx==9){ kx=0; p++; }
      }
    }
  }
  __syncthreads();

  // MFMA row B
  acc0 = (f32x4){0.f,0.f,0.f,0.f}; acc1 = acc0;
  #pragma unroll
  for (int kt=0;kt<8;kt++){
    int off0 = ((p0<<9)+(kt<<6)+colb) ^ sw0;
    int off1 = ((p1<<9)+(kt<<6)+colb) ^ sw1;
    bf16x8 bh0 = *(const bf16x8*)(smem+off0);
    bf16x8 bl0 = *(const bf16x8*)(smem+10240+off0);
    bf16x8 bh1 = *(const bf16x8*)(smem+off1);
    bf16x8 bl1 = *(const bf16x8*)(smem+10240+off1);
    acc0 = MFMA16(ah[kt], bh0, acc0);
    acc0 = MFMA16(ah[kt], bl0, acc0);
    acc0 = MFMA16(al[kt], bh0, acc0);
    acc1 = MFMA16(ah[kt], bh1, acc1);
    acc1 = MFMA16(ah[kt], bl1, acc1);
    acc1 = MFMA16(al[kt], bh1, acc1);
  }
  // pool row B + combine with row A — ALL lanes execute the shuffles; store predicated
  size_t ybase = (size_t)fr*6400 + g*10;
  #pragma unroll
  for (int reg=0;reg<4;reg++){
    int co = w*16 + ((l>>4)<<2) + reg;
    float v0 = fmaxf(acc0[reg]+bias[reg], 0.f);
    v0 = fmaxf(v0, __shfl_xor(v0,1));
    float r0 = fmaxf(vA0[reg], v0);
    float v1 = fmaxf(acc1[reg]+bias[reg], 0.f);
    v1 = fmaxf(v1, __shfl_xor(v1,1));
    float r1 = fmaxf(vA1[reg], v1);
    if ((m&1)==0){
      y1[ybase + co*100 + (m>>1)] = r0;
      if (m >= 12)
        y1[ybase + co*100 + ((4+m)>>1)] = r1;
    }
  }
}

// ================= conv2 (5x5 stride 5) + bias + relu + 2x2 maxpool -> y[640][3] =================
__global__ __launch_bounds__(256) void k_conv2(const float* __restrict__ y1,
                                               const float* __restrict__ W2,
                                               const float* __restrict__ b2,
                                               float* __restrict__ y2){
  __shared__ __align__(16) float yl[6400];
  __shared__ __align__(16) float w2s[4800];
  int fr = blockIdx.x, t = threadIdx.x;
  const float4* src = (const float4*)(y1 + (size_t)fr*6400);
  for (int i=t;i<1600;i+=256) async16(((float4*)yl) + i, (const void*)(src + i));
  for (int i=t;i<1200;i+=256) async16(((float4*)w2s) + i, (const void*)(((const float4*)W2) + i));
  __syncthreads();
  if (t < 192){
    int o = t>>4, l16 = t&15;
    int ch = o>>2, pos = o&3;
    int oy = pos>>1, ox = pos&1;
    float s = 0.f;
    for (int i=0;i<100;i++){
      int k = l16 + (i<<4);
      int ci = k/25; int r = k - ci*25; int ky = r/5, kx = r - ky*5;
      s += yl[ci*100 + (5*oy+ky)*10 + 5*ox + kx] * w2s[ch*1600 + k];
    }
    #pragma unroll
    for (int d=1; d<16; d<<=1) s += __shfl_xor(s, d);
    float v = fmaxf(s + b2[ch], 0.f);
    v = fmaxf(v, __shfl_xor(v, 16));
    v = fmaxf(v, __shfl_xor(v, 32));
    if ((t&63)==0) y2[fr*3 + (t>>6)] = v;
  }
}

// ================= fused BN(train)+sort + 3 RNNs (one block per RNN) =================
__global__ __launch_bounds__(512) void k_rnn(const unsigned short* __restrict__ whh_h,
                                             const unsigned short* __restrict__ whh_l,
                                             const float* __restrict__ y2,
                                             const float* __restrict__ gamma,
                                             const float* __restrict__ beta,
                                             const float* __restrict__ Wih,
                                             const float* __restrict__ bih,
                                             const float* __restrict__ bhh,
                                             float* __restrict__ lasts){
  __shared__ __align__(16) char hsm[36864];  // buf0 @0 (hi|lo 8K+8K), buf1 @16384, seqL @32768
  float* yl   = (float*)hsm;                 // [1920] overlaid in buf0 during phase A
  float* af   = (float*)(hsm + 7680);        // [64]
  float* bfv  = (float*)(hsm + 7936);        // [64]
  float* rngL = (float*)(hsm + 8192);        // [10][3]
  int*   perm = (int*)(hsm + 8320);          // [10][3]
  float* tsb  = (float*)(hsm + 8448);        // [10][3][64]
  float* seqL = (float*)(hsm + 32768);       // [64][16]
  int rnn = blockIdx.x;
  int t = threadIdx.x, w = t>>6, l = t&63;

  bf16x8 Bh[2][8], Bl[2][8];                 // wave w owns n-tiles 2w, 2w+1
  #pragma unroll
  for (int q=0;q<2;q++){
    int nt = 2*w + q;
    #pragma unroll
    for (int kt=0;kt<8;kt++){
      size_t fi = (((((size_t)rnn*16 + nt)*8) + kt)*64 + l)*8;
      Bh[q][kt] = *(const bf16x8*)(whh_h + fi);
      Bl[q][kt] = *(const bf16x8*)(whh_l + fi);
    }
  }
  int o0 = (2*w)*16 + (l&15), o1 = o0 + 16;
  float wih0 = Wih[rnn*256 + o0], wih1 = Wih[rnn*256 + o1];
  float bs0 = bih[rnn*256+o0] + bhh[rnn*256+o0];
  float bs1 = bih[rnn*256+o1] + bhh[rnn*256+o1];

  // ---- phase A: BN + sort + seq build ----
  for (int i=t;i<1920;i+=512) yl[i] = y2[i];
  __syncthreads();
  if (t < 64){
    float mu = 0.f;
    for (int b=0;b<10;b++)
      for (int ch=0;ch<3;ch++) mu += yl[(b*64 + t)*3 + ch];
    mu *= (1.f/30.f);
    float v = 0.f;
    for (int b=0;b<10;b++)
      for (int ch=0;ch<3;ch++){ float d = yl[(b*64+t)*3+ch] - mu; v += d*d; }
    v *= (1.f/30.f);
    float rs = rsqrtf(v + 1e-5f);
    float a = gamma[t]*rs;
    af[t] = a; bfv[t] = beta[t] - mu*a;
  }
  __syncthreads();
  if (t < 30){
    int b = t/3, ch = t - b*3;
    float mx = -1e30f, mn = 1e30f;
    for (int f=0; f<64; f++){
      float v = yl[(b*64+f)*3+ch]*af[f] + bfv[f];
      tsb[(b*3+ch)*64 + f] = v;
      mx = fmaxf(mx, v); mn = fminf(mn, v);
    }
    rngL[b*3+ch] = mx - mn;
  }
  __syncthreads();
  if (t < 10){
    #pragma unroll
    for (int ch=0; ch<3; ch++){
      float rc = rngL[t*3+ch];
      int rank = 0;
      #pragma unroll
      for (int c2=0; c2<3; c2++){
        float r2 = rngL[t*3+c2];
        if (r2 < rc || (r2 == rc && c2 < ch)) rank++;   // stable argsort ascending
      }
      perm[t*3+rank] = ch;
    }
  }
  __syncthreads();
  for (int i=t;i<1024;i+=512){
    int step = i>>4, b = i&15;
    float v = 0.f;
    if (b < 10){ int p = perm[b*3 + rnn]; v = tsb[(b*3+p)*64 + step]; }
    seqL[i] = v;
  }
  __syncthreads();

  // ---- phase B: recurrence ----
  float4 z4 = {0.f,0.f,0.f,0.f};
  for (int i=t; i<1024; i+=512) ((float4*)hsm)[i] = z4;   // zero buf0 (h=0)
  __syncthreads();
  int arow = l&15, colb = (l>>4)<<4, sw = (arow&7)<<4;
  int b_base = (l>>4)<<2;
  for (int step=0; step<64; step++){
    char* cur = hsm + ((step&1)<<14);
    char* nxt = hsm + (((step+1)&1)<<14);
    f32x4 p0=(f32x4){0,0,0,0}, q0=p0, r0=p0, p1=p0, q1=p0, r1=p0;
    #pragma unroll
    for (int kt=0; kt<8; kt++){
      int off = ((arow<<9) + (kt<<6) + colb) ^ sw;
      bf16x8 ahv = *(const bf16x8*)(cur + off);
      bf16x8 alv = *(const bf16x8*)(cur + 8192 + off);
      p0 = MFMA16(ahv, Bh[0][kt], p0);
      q0 = MFMA16(ahv, Bl[0][kt], q0);
      r0 = MFMA16(alv, Bh[0][kt], r0);
      p1 = MFMA16(ahv, Bh[1][kt], p1);
      q1 = MFMA16(ahv, Bl[1][kt], q1);
      r1 = MFMA16(alv, Bh[1][kt], r1);
    }
    float4 sx = *(const float4*)(seqL + (step<<4) + b_base);
    float sxa[4] = {sx.x, sx.y, sx.z, sx.w};
    #pragma unroll
    for (int reg=0; reg<4; reg++){
      int b = b_base + reg;
      float a0 = (p0[reg] + q0[reg]) + r0[reg];
      float a1 = (p1[reg] + q1[reg]) + r1[reg];
      float h0 = tanh_fast(a0 + sxa[reg]*wih0 + bs0);
      float h1 = tanh_fast(a1 + sxa[reg]*wih1 + bs1);
      int wsw = (b&7)<<4;
      int off0 = ((b<<9) + (o0<<1)) ^ wsw;
      int off1 = ((b<<9) + (o1<<1)) ^ wsw;
      unsigned int u0 = __float_as_uint(h0);
      unsigned int u1 = __float_as_uint(h1);
      *(unsigned short*)(nxt + off0) = (unsigned short)(u0>>16);
      float l0 = h0 - __uint_as_float(u0 & 0xffff0000u);
      *(unsigned short*)(nxt + 8192 + off0) = (unsigned short)(__float_as_uint(l0)>>16);
      *(unsigned short*)(nxt + off1) = (unsigned short)(u1>>16);
      float l1 = h1 - __uint_as_float(u1 & 0xffff0000u);
      *(unsigned short*)(nxt + 8192 + off1) = (unsigned short)(__float_as_uint(l1)>>16);
      if (step == 63){
        lasts[((size_t)rnn*16 + b)*256 + o0] = h0;
        lasts[((size_t)rnn*16 + b)*256 + o1] = h1;
      }
    }
    __syncthreads();
  }
}

// ================= head: avg over 3 RNNs, @ Wl^T + bl -> out[10][5] =================
__global__ __launch_bounds__(512) void k_head(const float* __restrict__ lasts,
                                              const float* __restrict__ Wl,
                                              const float* __restrict__ bl,
                                              float* __restrict__ out){
  int t = threadIdx.x;
  if (t < 400){
    int oidx = t>>3, l8 = t&7;       // 50 outputs x 8 lanes
    int b = oidx/5, c = oidx - b*5;
    float s = 0.f;
    for (int i=0;i<32;i++){
      int o = (l8<<5) + i;
      float avg = (lasts[(size_t)(0*16+b)*256+o] + lasts[(size_t)(1*16+b)*256+o]
                 + lasts[(size_t)(2*16+b)*256+o]) * (1.f/3.f);
      s += avg * Wl[c*256 + o];
    }
    #pragma unroll
    for (int d=1; d<8; d<<=1) s += __shfl_xor(s, d);
    if (l8 == 0) out[oidx] = s + bl[c];
  }
}

extern "C" void kernel_launch(void* const* d_in, const int* in_sizes, int n_in,
                              void* d_out, int out_size, void* d_ws, size_t ws_size,
                              hipStream_t stream){
  const float* x    = (const float*)d_in[0];
  const float* W1   = (const float*)d_in[1];
  const float* b1   = (const float*)d_in[2];
  const float* W2   = (const float*)d_in[3];
  const float* b2   = (const float*)d_in[4];
  const float* gamma= (const float*)d_in[5];
  const float* beta = (const float*)d_in[6];
  const float* Wih  = (const float*)d_in[7];
  const float* Whh  = (const float*)d_in[8];
  const float* bih  = (const float*)d_in[9];
  const float* bhh  = (const float*)d_in[10];
  const float* Wl   = (const float*)d_in[11];
  const float* bl   = (const float*)d_in[12];
  char* ws = (char*)d_ws;
  unsigned short* w1h  = (unsigned short*)(ws + WS_W1H);
  unsigned short* w1l  = (unsigned short*)(ws + WS_W1L);
  unsigned short* whhh = (unsigned short*)(ws + WS_WHHH);
  unsigned short* whhl = (unsigned short*)(ws + WS_WHHL);
  float* y1   = (float*)(ws + WS_Y1);
  float* y2   = (float*)(ws + WS_Y2);
  float* last = (float*)(ws + WS_LAST);

  hipLaunchKernelGGL(k_prep,  dim3(104),  dim3(256), 0, stream, W1, Whh, w1h, w1l, whhh, whhl);
  hipLaunchKernelGGL(k_conv1, dim3(6400), dim3(256), 0, stream, x, b1, w1h, w1l, y1);
  hipLaunchKernelGGL(k_conv2, dim3(640),  dim3(256), 0, stream, y1, W2, b2, y2);
  hipLaunchKernelGGL(k_rnn,   dim3(3),    dim3(512), 0, stream, whhh, whhl, y2, gamma, beta, Wih, bih, bhh, last);
  hipLaunchKernelGGL(k_head,  dim3(1),    dim3(512), 0, stream, last, Wl, bl, (float*)d_out);
}

// Round 7
// 204.322 us; speedup vs baseline: 2.2204x; 1.4947x over previous
//
#include <hip/hip_runtime.h>

typedef __attribute__((ext_vector_type(8))) short bf16x8;
typedef __attribute__((ext_vector_type(4))) float f32x4;

#define MFMA16(a,b,c) __builtin_amdgcn_mfma_f32_16x16x32_bf16((a),(b),(c),0,0,0)

#define AS1 __attribute__((address_space(1)))
#define AS3 __attribute__((address_space(3)))
__device__ __forceinline__ void async16(void* lds, const void* g){
  __builtin_amdgcn_global_load_lds((const AS1 unsigned int*)g, (AS3 unsigned int*)lds, 16, 0, 0);
}

__device__ __forceinline__ unsigned short f2bf(float f){
  unsigned int u = __float_as_uint(f);
  unsigned int r = (u + 0x7fffu + ((u>>16)&1u)) >> 16;
  return (unsigned short)r;
}
__device__ __forceinline__ float bf2f(unsigned short h){
  return __uint_as_float(((unsigned int)h)<<16);
}
__device__ __forceinline__ float tanh_fast(float x){
  float e = __expf(2.f*x);
  return 1.f - 2.f/(e + 1.f);
}

// ---- workspace byte offsets ----
#define WS_W1H   0u           // [4 mt][8 kt][64 lane][8] bf16 hi  (32768 B)
#define WS_W1L   32768u
#define WS_WHHH  65536u       // [3][16 nt][8 kt][64][8] bf16 hi   (393216 B)
#define WS_WHHL  458752u
#define WS_Y1    851968u      // [640][64][10][10] f32             (16384000 B)
#define WS_Y2    17235968u    // [640][3] f32
#define WS_LAST  17255936u    // [3][16][256] f32

// ================= prep: split W1 / Whh into MFMA fragment layout =================
__global__ __launch_bounds__(256) void k_prep(const float* __restrict__ W1,
                                              const float* __restrict__ Whh,
                                              unsigned short* __restrict__ w1h,
                                              unsigned short* __restrict__ w1l,
                                              unsigned short* __restrict__ whh_h,
                                              unsigned short* __restrict__ whh_l){
  int t = blockIdx.x*256 + threadIdx.x;
  if (t < 2048){
    int l = t & 63, kt = (t>>6)&7, mt = t>>9;
    int co = mt*16 + (l&15);
    int k0 = kt*32 + ((l>>4)<<3);
    bf16x8 hv, lv;
    #pragma unroll
    for (int j=0;j<8;j++){
      int k = k0 + j;
      float v = (k < 243) ? W1[co*243 + k] : 0.f;
      unsigned short h = f2bf(v);
      unsigned short lo = f2bf(v - bf2f(h));
      hv[j] = (short)h; lv[j] = (short)lo;
    }
    *(bf16x8*)(w1h + (size_t)t*8) = hv;
    *(bf16x8*)(w1l + (size_t)t*8) = lv;
  } else if (t < 2048 + 24576){
    int u = t - 2048;
    int l = u & 63, kt = (u>>6)&7, nt = (u>>9)&15, rnn = u>>13;
    int o = nt*16 + (l&15);
    int k0 = kt*32 + ((l>>4)<<3);
    const float* src = Whh + ((size_t)rnn*256 + o)*256;
    bf16x8 hv, lv;
    #pragma unroll
    for (int j=0;j<8;j++){
      float v = src[k0 + j];
      unsigned short h = f2bf(v);
      unsigned short lo = f2bf(v - bf2f(h));
      hv[j] = (short)h; lv[j] = (short)lo;
    }
    *(bf16x8*)(whh_h + (size_t)u*8) = hv;
    *(bf16x8*)(whh_l + (size_t)u*8) = lv;
  }
}

// ================= conv1 (9x9 stride 9) + bias + relu + 2x2 maxpool =================
// block = (frame, oy-pair g); rows 2g,2g+1 processed SEQUENTIALLY in the same 20-patch
// B-planes. LDS = 20480 B. PLAIN __launch_bounds__(256): no VGPR cap — the (256,N)
// variants capped VGPRs at 256/N (64/32) and spilled ~300 MB to scratch. ~120-VGPR
// demand -> compiler picks ~128 -> 4 blocks/CU, zero spills.
__global__ __launch_bounds__(256) void k_conv1(const float* __restrict__ x,
                                               const float* __restrict__ b1,
                                               const unsigned short* __restrict__ w1h,
                                               const unsigned short* __restrict__ w1l,
                                               float* __restrict__ y1){
  __shared__ __align__(16) char smem[20480];   // hi[20][256]bf16 @0, lo @10240, XOR-swizzled
  int fr = blockIdx.x/10, g = blockIdx.x%10;
  int t = threadIdx.x, w = t>>6, l = t&63;

  // A = W1 fragments (split), one co-tile per wave
  bf16x8 ah[8], al[8];
  #pragma unroll
  for (int kt=0;kt<8;kt++){
    size_t fi = (((size_t)(w*8+kt))*64 + l)*8;
    ah[kt] = *(const bf16x8*)(w1h+fi);
    al[kt] = *(const bf16x8*)(w1l+fi);
  }
  float bias[4];
  #pragma unroll
  for (int reg=0;reg<4;reg++) bias[reg] = b1[w*16 + ((l>>4)<<2) + reg];

  const float4* xb = (const float4*)x + (size_t)fr*24300;
  int rowbase = g*18;

  // per-thread scatter mapping (identical for both rows)
  float4 rv[5]; int pp[5], kk[5], kxv[5]; bool okv[5];
  #pragma unroll
  for (int ii=0; ii<5; ii++){
    int i = t + (ii<<8);
    okv[ii] = (i < 1215);
    int c = i/405, rem = i - c*405;
    int ky = rem/45, quad = rem - ky*45;
    int col0 = quad<<2;
    int ox = (col0*57)>>9;           // floor(col0/9) for col0<180
    kxv[ii] = col0 - 9*ox;
    pp[ii] = ox;
    kk[ii] = c*81 + ky*9;
    int gi = c*8100 + (rowbase + ky)*45 + quad;
    rv[ii] = okv[ii] ? xb[gi] : (float4){0.f,0.f,0.f,0.f};   // row A loads in flight
  }
  // zero pad k in [243,256) once; persists across both rows
  for (int i=t; i<260; i+=256){
    int p = i/13, k = 243 + (i - p*13);
    int off = ((p<<9)+(k<<1)) ^ ((p&7)<<4);
    *(unsigned short*)(smem+off) = 0;
    *(unsigned short*)(smem+10240+off) = 0;
  }
  // scatter row A (waits on rv here)
  #pragma unroll
  for (int ii=0; ii<5; ii++){
    if (okv[ii]){
      int p = pp[ii], kx = kxv[ii];
      float vv[4] = {rv[ii].x, rv[ii].y, rv[ii].z, rv[ii].w};
      #pragma unroll
      for (int q=0;q<4;q++){
        int k = kk[ii] + kx;
        int off = ((p<<9)+(k<<1)) ^ ((p&7)<<4);
        unsigned int u = __float_as_uint(vv[q]);
        *(unsigned short*)(smem+off) = (unsigned short)(u>>16);
        float lof = vv[q] - __uint_as_float(u & 0xffff0000u);
        *(unsigned short*)(smem+10240+off) = (unsigned short)(__float_as_uint(lof)>>16);
        kx++; if (kx==9){ kx=0; p++; }
      }
    }
  }
  __syncthreads();

  // issue row B loads NOW — they fly under row A's MFMA phase
  #pragma unroll
  for (int ii=0; ii<5; ii++){
    int i = t + (ii<<8);
    int c = i/405, rem = i - c*405;
    int ky = rem/45, quad = rem - ky*45;
    int gi = c*8100 + (rowbase + 9 + ky)*45 + quad;
    rv[ii] = okv[ii] ? xb[gi] : (float4){0.f,0.f,0.f,0.f};
  }

  // MFMA row A: n-tiles at patches {0..15} and {4..19}
  int m = l&15, colb = (l>>4)<<4;
  int p0 = m, p1 = 4+m;
  int sw0 = (p0&7)<<4, sw1 = (p1&7)<<4;
  f32x4 acc0 = (f32x4){0.f,0.f,0.f,0.f}, acc1 = acc0;
  #pragma unroll
  for (int kt=0;kt<8;kt++){
    int off0 = ((p0<<9)+(kt<<6)+colb) ^ sw0;
    int off1 = ((p1<<9)+(kt<<6)+colb) ^ sw1;
    bf16x8 bh0 = *(const bf16x8*)(smem+off0);
    bf16x8 bl0 = *(const bf16x8*)(smem+10240+off0);
    bf16x8 bh1 = *(const bf16x8*)(smem+off1);
    bf16x8 bl1 = *(const bf16x8*)(smem+10240+off1);
    acc0 = MFMA16(ah[kt], bh0, acc0);
    acc0 = MFMA16(ah[kt], bl0, acc0);
    acc0 = MFMA16(al[kt], bh0, acc0);
    acc1 = MFMA16(ah[kt], bh1, acc1);
    acc1 = MFMA16(ah[kt], bl1, acc1);
    acc1 = MFMA16(al[kt], bh1, acc1);
  }
  // pool row A horizontally into registers (all lanes, uniform shuffles)
  float vA0[4], vA1[4];
  #pragma unroll
  for (int reg=0;reg<4;reg++){
    float v0 = fmaxf(acc0[reg]+bias[reg], 0.f);
    vA0[reg] = fmaxf(v0, __shfl_xor(v0,1));
    float v1 = fmaxf(acc1[reg]+bias[reg], 0.f);
    vA1[reg] = fmaxf(v1, __shfl_xor(v1,1));
  }
  __syncthreads();   // all waves done reading row-A planes

  // scatter row B
  #pragma unroll
  for (int ii=0; ii<5; ii++){
    if (okv[ii]){
      int p = pp[ii], kx = kxv[ii];
      float vv[4] = {rv[ii].x, rv[ii].y, rv[ii].z, rv[ii].w};
      #pragma unroll
      for (int q=0;q<4;q++){
        int k = kk[ii] + kx;
        int off = ((p<<9)+(k<<1)) ^ ((p&7)<<4);
        unsigned int u = __float_as_uint(vv[q]);
        *(unsigned short*)(smem+off) = (unsigned short)(u>>16);
        float lof = vv[q] - __uint_as_float(u & 0xffff0000u);
        *(unsigned short*)(smem+10240+off) = (unsigned short)(__float_as_uint(lof)>>16);
        kx++; if (kx==9){ kx=0; p++; }
      }
    }
  }
  __syncthreads();

  // MFMA row B
  acc0 = (f32x4){0.f,0.f,0.f,0.f}; acc1 = acc0;
  #pragma unroll
  for (int kt=0;kt<8;kt++){
    int off0 = ((p0<<9)+(kt<<6)+colb) ^ sw0;
    int off1 = ((p1<<9)+(kt<<6)+colb) ^ sw1;
    bf16x8 bh0 = *(const bf16x8*)(smem+off0);
    bf16x8 bl0 = *(const bf16x8*)(smem+10240+off0);
    bf16x8 bh1 = *(const bf16x8*)(smem+off1);
    bf16x8 bl1 = *(const bf16x8*)(smem+10240+off1);
    acc0 = MFMA16(ah[kt], bh0, acc0);
    acc0 = MFMA16(ah[kt], bl0, acc0);
    acc0 = MFMA16(al[kt], bh0, acc0);
    acc1 = MFMA16(ah[kt], bh1, acc1);
    acc1 = MFMA16(ah[kt], bl1, acc1);
    acc1 = MFMA16(al[kt], bh1, acc1);
  }
  // pool row B + combine with row A — ALL lanes execute the shuffles; store predicated
  size_t ybase = (size_t)fr*6400 + g*10;
  #pragma unroll
  for (int reg=0;reg<4;reg++){
    int co = w*16 + ((l>>4)<<2) + reg;
    float v0 = fmaxf(acc0[reg]+bias[reg], 0.f);
    v0 = fmaxf(v0, __shfl_xor(v0,1));
    float r0 = fmaxf(vA0[reg], v0);
    float v1 = fmaxf(acc1[reg]+bias[reg], 0.f);
    v1 = fmaxf(v1, __shfl_xor(v1,1));
    float r1 = fmaxf(vA1[reg], v1);
    if ((m&1)==0){
      y1[ybase + co*100 + (m>>1)] = r0;
      if (m >= 12)
        y1[ybase + co*100 + ((4+m)>>1)] = r1;
    }
  }
}

// ================= conv2 (5x5 stride 5) + bias + relu + 2x2 maxpool -> y[640][3] =================
__global__ __launch_bounds__(256) void k_conv2(const float* __restrict__ y1,
                                               const float* __restrict__ W2,
                                               const float* __restrict__ b2,
                                               float* __restrict__ y2){
  __shared__ __align__(16) float yl[6400];
  __shared__ __align__(16) float w2s[4800];
  int fr = blockIdx.x, t = threadIdx.x;
  const float4* src = (const float4*)(y1 + (size_t)fr*6400);
  for (int i=t;i<1600;i+=256) async16(((float4*)yl) + i, (const void*)(src + i));
  for (int i=t;i<1200;i+=256) async16(((float4*)w2s) + i, (const void*)(((const float4*)W2) + i));
  __syncthreads();
  if (t < 192){
    int o = t>>4, l16 = t&15;
    int ch = o>>2, pos = o&3;
    int oy = pos>>1, ox = pos&1;
    float s = 0.f;
    for (int i=0;i<100;i++){
      int k = l16 + (i<<4);
      int ci = k/25; int r = k - ci*25; int ky = r/5, kx = r - ky*5;
      s += yl[ci*100 + (5*oy+ky)*10 + 5*ox + kx] * w2s[ch*1600 + k];
    }
    #pragma unroll
    for (int d=1; d<16; d<<=1) s += __shfl_xor(s, d);
    float v = fmaxf(s + b2[ch], 0.f);
    v = fmaxf(v, __shfl_xor(v, 16));
    v = fmaxf(v, __shfl_xor(v, 32));
    if ((t&63)==0) y2[fr*3 + (t>>6)] = v;
  }
}

// ================= fused BN(train)+sort + 3 RNNs (one block per RNN) =================
__global__ __launch_bounds__(512) void k_rnn(const unsigned short* __restrict__ whh_h,
                                             const unsigned short* __restrict__ whh_l,
                                             const float* __restrict__ y2,
                                             const float* __restrict__ gamma,
                                             const float* __restrict__ beta,
                                             const float* __restrict__ Wih,
                                             const float* __restrict__ bih,
                                             const float* __restrict__ bhh,
                                             float* __restrict__ lasts){
  __shared__ __align__(16) char hsm[36864];  // buf0 @0 (hi|lo 8K+8K), buf1 @16384, seqL @32768
  float* yl   = (float*)hsm;                 // [1920] overlaid in buf0 during phase A
  float* af   = (float*)(hsm + 7680);        // [64]
  float* bfv  = (float*)(hsm + 7936);        // [64]
  float* rngL = (float*)(hsm + 8192);        // [10][3]
  int*   perm = (int*)(hsm + 8320);          // [10][3]
  float* tsb  = (float*)(hsm + 8448);        // [10][3][64]
  float* seqL = (float*)(hsm + 32768);       // [64][16]
  int rnn = blockIdx.x;
  int t = threadIdx.x, w = t>>6, l = t&63;

  bf16x8 Bh[2][8], Bl[2][8];                 // wave w owns n-tiles 2w, 2w+1
  #pragma unroll
  for (int q=0;q<2;q++){
    int nt = 2*w + q;
    #pragma unroll
    for (int kt=0;kt<8;kt++){
      size_t fi = (((((size_t)rnn*16 + nt)*8) + kt)*64 + l)*8;
      Bh[q][kt] = *(const bf16x8*)(whh_h + fi);
      Bl[q][kt] = *(const bf16x8*)(whh_l + fi);
    }
  }
  int o0 = (2*w)*16 + (l&15), o1 = o0 + 16;
  float wih0 = Wih[rnn*256 + o0], wih1 = Wih[rnn*256 + o1];
  float bs0 = bih[rnn*256+o0] + bhh[rnn*256+o0];
  float bs1 = bih[rnn*256+o1] + bhh[rnn*256+o1];

  // ---- phase A: BN + sort + seq build ----
  for (int i=t;i<1920;i+=512) yl[i] = y2[i];
  __syncthreads();
  if (t < 64){
    float mu = 0.f;
    for (int b=0;b<10;b++)
      for (int ch=0;ch<3;ch++) mu += yl[(b*64 + t)*3 + ch];
    mu *= (1.f/30.f);
    float v = 0.f;
    for (int b=0;b<10;b++)
      for (int ch=0;ch<3;ch++){ float d = yl[(b*64+t)*3+ch] - mu; v += d*d; }
    v *= (1.f/30.f);
    float rs = rsqrtf(v + 1e-5f);
    float a = gamma[t]*rs;
    af[t] = a; bfv[t] = beta[t] - mu*a;
  }
  __syncthreads();
  if (t < 30){
    int b = t/3, ch = t - b*3;
    float mx = -1e30f, mn = 1e30f;
    for (int f=0; f<64; f++){
      float v = yl[(b*64+f)*3+ch]*af[f] + bfv[f];
      tsb[(b*3+ch)*64 + f] = v;
      mx = fmaxf(mx, v); mn = fminf(mn, v);
    }
    rngL[b*3+ch] = mx - mn;
  }
  __syncthreads();
  if (t < 10){
    #pragma unroll
    for (int ch=0; ch<3; ch++){
      float rc = rngL[t*3+ch];
      int rank = 0;
      #pragma unroll
      for (int c2=0; c2<3; c2++){
        float r2 = rngL[t*3+c2];
        if (r2 < rc || (r2 == rc && c2 < ch)) rank++;   // stable argsort ascending
      }
      perm[t*3+rank] = ch;
    }
  }
  __syncthreads();
  for (int i=t;i<1024;i+=512){
    int step = i>>4, b = i&15;
    float v = 0.f;
    if (b < 10){ int p = perm[b*3 + rnn]; v = tsb[(b*3+p)*64 + step]; }
    seqL[i] = v;
  }
  __syncthreads();

  // ---- phase B: recurrence ----
  float4 z4 = {0.f,0.f,0.f,0.f};
  for (int i=t; i<1024; i+=512) ((float4*)hsm)[i] = z4;   // zero buf0 (h=0)
  __syncthreads();
  int arow = l&15, colb = (l>>4)<<4, sw = (arow&7)<<4;
  int b_base = (l>>4)<<2;
  for (int step=0; step<64; step++){
    char* cur = hsm + ((step&1)<<14);
    char* nxt = hsm + (((step+1)&1)<<14);
    f32x4 p0=(f32x4){0,0,0,0}, q0=p0, r0=p0, p1=p0, q1=p0, r1=p0;
    #pragma unroll
    for (int kt=0; kt<8; kt++){
      int off = ((arow<<9) + (kt<<6) + colb) ^ sw;
      bf16x8 ahv = *(const bf16x8*)(cur + off);
      bf16x8 alv = *(const bf16x8*)(cur + 8192 + off);
      p0 = MFMA16(ahv, Bh[0][kt], p0);
      q0 = MFMA16(ahv, Bl[0][kt], q0);
      r0 = MFMA16(alv, Bh[0][kt], r0);
      p1 = MFMA16(ahv, Bh[1][kt], p1);
      q1 = MFMA16(ahv, Bl[1][kt], q1);
      r1 = MFMA16(alv, Bh[1][kt], r1);
    }
    float4 sx = *(const float4*)(seqL + (step<<4) + b_base);
    float sxa[4] = {sx.x, sx.y, sx.z, sx.w};
    #pragma unroll
    for (int reg=0; reg<4; reg++){
      int b = b_base + reg;
      float a0 = (p0[reg] + q0[reg]) + r0[reg];
      float a1 = (p1[reg] + q1[reg]) + r1[reg];
      float h0 = tanh_fast(a0 + sxa[reg]*wih0 + bs0);
      float h1 = tanh_fast(a1 + sxa[reg]*wih1 + bs1);
      int wsw = (b&7)<<4;
      int off0 = ((b<<9) + (o0<<1)) ^ wsw;
      int off1 = ((b<<9) + (o1<<1)) ^ wsw;
      unsigned int u0 = __float_as_uint(h0);
      unsigned int u1 = __float_as_uint(h1);
      *(unsigned short*)(nxt + off0) = (unsigned short)(u0>>16);
      float l0 = h0 - __uint_as_float(u0 & 0xffff0000u);
      *(unsigned short*)(nxt + 8192 + off0) = (unsigned short)(__float_as_uint(l0)>>16);
      *(unsigned short*)(nxt + off1) = (unsigned short)(u1>>16);
      float l1 = h1 - __uint_as_float(u1 & 0xffff0000u);
      *(unsigned short*)(nxt + 8192 + off1) = (unsigned short)(__float_as_uint(l1)>>16);
      if (step == 63){
        lasts[((size_t)rnn*16 + b)*256 + o0] = h0;
        lasts[((size_t)rnn*16 + b)*256 + o1] = h1;
      }
    }
    __syncthreads();
  }
}

// ================= head: avg over 3 RNNs, @ Wl^T + bl -> out[10][5] =================
__global__ __launch_bounds__(512) void k_head(const float* __restrict__ lasts,
                                              const float* __restrict__ Wl,
                                              const float* __restrict__ bl,
                                              float* __restrict__ out){
  int t = threadIdx.x;
  if (t < 400){
    int oidx = t>>3, l8 = t&7;       // 50 outputs x 8 lanes
    int b = oidx/5, c = oidx - b*5;
    float s = 0.f;
    for (int i=0;i<32;i++){
      int o = (l8<<5) + i;
      float avg = (lasts[(size_t)(0*16+b)*256+o] + lasts[(size_t)(1*16+b)*256+o]
                 + lasts[(size_t)(2*16+b)*256+o]) * (1.f/3.f);
      s += avg * Wl[c*256 + o];
    }
    #pragma unroll
    for (int d=1; d<8; d<<=1) s += __shfl_xor(s, d);
    if (l8 == 0) out[oidx] = s + bl[c];
  }
}

extern "C" void kernel_launch(void* const* d_in, const int* in_sizes, int n_in,
                              void* d_out, int out_size, void* d_ws, size_t ws_size,
                              hipStream_t stream){
  const float* x    = (const float*)d_in[0];
  const float* W1   = (const float*)d_in[1];
  const float* b1   = (const float*)d_in[2];
  const float* W2   = (const float*)d_in[3];
  const float* b2   = (const float*)d_in[4];
  const float* gamma= (const float*)d_in[5];
  const float* beta = (const float*)d_in[6];
  const float* Wih  = (const float*)d_in[7];
  const float* Whh  = (const float*)d_in[8];
  const float* bih  = (const float*)d_in[9];
  const float* bhh  = (const float*)d_in[10];
  const float* Wl   = (const float*)d_in[11];
  const float* bl   = (const float*)d_in[12];
  char* ws = (char*)d_ws;
  unsigned short* w1h  = (unsigned short*)(ws + WS_W1H);
  unsigned short* w1l  = (unsigned short*)(ws + WS_W1L);
  unsigned short* whhh = (unsigned short*)(ws + WS_WHHH);
  unsigned short* whhl = (unsigned short*)(ws + WS_WHHL);
  float* y1   = (float*)(ws + WS_Y1);
  float* y2   = (float*)(ws + WS_Y2);
  float* last = (float*)(ws + WS_LAST);

  hipLaunchKernelGGL(k_prep,  dim3(104),  dim3(256), 0, stream, W1, Whh, w1h, w1l, whhh, whhl);
  hipLaunchKernelGGL(k_conv1, dim3(6400), dim3(256), 0, stream, x, b1, w1h, w1l, y1);
  hipLaunchKernelGGL(k_conv2, dim3(640),  dim3(256), 0, stream, y1, W2, b2, y2);
  hipLaunchKernelGGL(k_rnn,   dim3(3),    dim3(512), 0, stream, whhh, whhl, y2, gamma, beta, Wih, bih, bhh, last);
  hipLaunchKernelGGL(k_head,  dim3(1),    dim3(512), 0, stream, last, Wl, bl, (float*)d_out);
}

// Round 8
// 180.420 us; speedup vs baseline: 2.5145x; 1.1325x over previous
//
#include <hip/hip_runtime.h>

typedef __attribute__((ext_vector_type(8))) short bf16x8;
typedef __attribute__((ext_vector_type(4))) float f32x4;

#define MFMA16(a,b,c) __builtin_amdgcn_mfma_f32_16x16x32_bf16((a),(b),(c),0,0,0)

#define AS1 __attribute__((address_space(1)))
#define AS3 __attribute__((address_space(3)))
__device__ __forceinline__ void async16(void* lds, const void* g){
  __builtin_amdgcn_global_load_lds((const AS1 unsigned int*)g, (AS3 unsigned int*)lds, 16, 0, 0);
}

__device__ __forceinline__ unsigned short f2bf(float f){
  unsigned int u = __float_as_uint(f);
  unsigned int r = (u + 0x7fffu + ((u>>16)&1u)) >> 16;
  return (unsigned short)r;
}
__device__ __forceinline__ float bf2f(unsigned short h){
  return __uint_as_float(((unsigned int)h)<<16);
}
__device__ __forceinline__ float tanh_fast(float x){
  float e = __expf(2.f*x);
  return 1.f - 2.f/(e + 1.f);
}

// ---- workspace byte offsets ----
#define WS_W1H   0u           // [4 mt][8 kt][64 lane][8] bf16 hi  (32768 B)
#define WS_W1L   32768u
#define WS_WHHH  65536u       // [3][16 nt][8 kt][64][8] bf16 hi   (393216 B)
#define WS_WHHL  458752u
#define WS_Y1    851968u      // [640][64][10][10] f32             (16384000 B)
#define WS_Y2    17235968u    // [640][3] f32
#define WS_LAST  17255936u    // [3][16][256] f32

// ---- conv1 k-ordering σ: k' = 8*o + j ----
// o<27: rowslice rs=o (c=o/9, ky=o%9), kx=j (0..7) -> korig = o*9+j  [8 CONTIGUOUS cols]
// o in 27..30: idx=(o-27)*8+j; valid iff idx<27: rs=idx, kx=8 -> korig = idx*9+8
// o=31: zero pad. Bijective onto [0,243); A and B both use σ so the MFMA sum is invariant.

// ================= prep: split W1 / Whh into MFMA fragment layout =================
__global__ __launch_bounds__(256) void k_prep(const float* __restrict__ W1,
                                              const float* __restrict__ Whh,
                                              unsigned short* __restrict__ w1h,
                                              unsigned short* __restrict__ w1l,
                                              unsigned short* __restrict__ whh_h,
                                              unsigned short* __restrict__ whh_l){
  int t = blockIdx.x*256 + threadIdx.x;
  if (t < 2048){
    int l = t & 63, kt = (t>>6)&7, mt = t>>9;
    int co = mt*16 + (l&15);
    int o = (kt*32 + ((l>>4)<<3)) >> 3;   // octet of this 8-k group
    bf16x8 hv, lv;
    #pragma unroll
    for (int j=0;j<8;j++){
      float v = 0.f;
      if (o < 27){
        v = W1[co*243 + o*9 + j];
      } else if (o < 31){
        int idx = (o-27)*8 + j;
        if (idx < 27) v = W1[co*243 + idx*9 + 8];
      }
      unsigned short h = f2bf(v);
      unsigned short lo = f2bf(v - bf2f(h));
      hv[j] = (short)h; lv[j] = (short)lo;
    }
    *(bf16x8*)(w1h + (size_t)t*8) = hv;
    *(bf16x8*)(w1l + (size_t)t*8) = lv;
  } else if (t < 2048 + 24576){
    int u = t - 2048;
    int l = u & 63, kt = (u>>6)&7, nt = (u>>9)&15, rnn = u>>13;
    int o = nt*16 + (l&15);
    int k0 = kt*32 + ((l>>4)<<3);
    const float* src = Whh + ((size_t)rnn*256 + o)*256;
    bf16x8 hv, lv;
    #pragma unroll
    for (int j=0;j<8;j++){
      float v = src[k0 + j];
      unsigned short h = f2bf(v);
      unsigned short lo = f2bf(v - bf2f(h));
      hv[j] = (short)h; lv[j] = (short)lo;
    }
    *(bf16x8*)(whh_h + (size_t)u*8) = hv;
    *(bf16x8*)(whh_l + (size_t)u*8) = lv;
  }
}

// ---- conv1 staging helpers: chunk = (octet o, patch p), ch = o*20+p ----
__device__ __forceinline__ void load_chunk(const float* __restrict__ xf, int rowbase,
                                           int ch, float* __restrict__ f){
  int o = (ch*205)>>12;          // ch/20 for ch<640
  int p = ch - 20*o;
  if (o < 27){
    int c = (o*57)>>9;           // o/9
    int ky = o - 9*c;
    const float* b = xf + c*32400 + (rowbase+ky)*180 + 9*p;
    #pragma unroll
    for (int j=0;j<8;j++) f[j] = b[j];          // 8 contiguous dwords
  } else if (o < 31){
    #pragma unroll
    for (int j=0;j<8;j++){
      int idx = (o-27)*8 + j;
      int cc = (idx*57)>>9;
      int kky = idx - 9*cc;
      f[j] = (idx<27) ? xf[cc*32400 + (rowbase+kky)*180 + 9*p + 8] : 0.f;
    }
  } else {
    #pragma unroll
    for (int j=0;j<8;j++) f[j] = 0.f;
  }
}

__device__ __forceinline__ void write_chunk(char* __restrict__ smem, int ch,
                                            const float* __restrict__ f){
  unsigned int hw[4], lw[4];
  #pragma unroll
  for (int i=0;i<4;i++){
    unsigned int ua = __float_as_uint(f[2*i]), ub = __float_as_uint(f[2*i+1]);
    float la = f[2*i]   - __uint_as_float(ua & 0xffff0000u);
    float lb = f[2*i+1] - __uint_as_float(ub & 0xffff0000u);
    hw[i] = __builtin_amdgcn_perm(ub, ua, 0x07060302u);                 // [a.hi | b.hi]
    lw[i] = __builtin_amdgcn_perm(__float_as_uint(lb), __float_as_uint(la), 0x07060302u);
  }
  *(uint4*)(smem + ch*16)         = make_uint4(hw[0],hw[1],hw[2],hw[3]);
  *(uint4*)(smem + 10240 + ch*16) = make_uint4(lw[0],lw[1],lw[2],lw[3]);
}

// ================= conv1 (9x9 stride 9) + bias + relu + 2x2 maxpool =================
// block = (frame, oy-pair g); rows 2g,2g+1 sequential in the same 20-patch planes.
// LDS 20480 B: hi [32 oct][20 p][8 bf16] @0, lo @10240. Chunk staging: 8 contiguous
// dword loads -> perm-packed split-bf16 -> ONE b128 write per plane (conflict-free,
// replaces the 40x ds_write_b16 scatter). Reads [o][p] layout: bank-balanced.
__global__ __launch_bounds__(256) void k_conv1(const float* __restrict__ x,
                                               const float* __restrict__ b1,
                                               const unsigned short* __restrict__ w1h,
                                               const unsigned short* __restrict__ w1l,
                                               float* __restrict__ y1){
  __shared__ __align__(16) char smem[20480];
  int fr = blockIdx.x/10, g = blockIdx.x%10;
  int t = threadIdx.x, w = t>>6, l = t&63;
  const float* xf = x + (size_t)fr*97200;
  int rb = g*18;

  // row A chunk loads in flight (chunks t, t+256, and t+512 for t<128)
  float f0[8], f1[8], f2[8];
  load_chunk(xf, rb, t,      f0);
  load_chunk(xf, rb, t+256,  f1);
  if (t < 128) load_chunk(xf, rb, t+512, f2);

  // A = W1 fragments (split), one co-tile per wave — overlaps load flight
  bf16x8 ah[8], al[8];
  #pragma unroll
  for (int kt=0;kt<8;kt++){
    size_t fi = (((size_t)(w*8+kt))*64 + l)*8;
    ah[kt] = *(const bf16x8*)(w1h+fi);
    al[kt] = *(const bf16x8*)(w1l+fi);
  }
  float bias[4];
  #pragma unroll
  for (int reg=0;reg<4;reg++) bias[reg] = b1[w*16 + ((l>>4)<<2) + reg];

  // convert + write row A
  write_chunk(smem, t,     f0);
  write_chunk(smem, t+256, f1);
  if (t < 128) write_chunk(smem, t+512, f2);
  __syncthreads();

  // issue row B loads NOW — fly under row A's MFMA phase (regs reusable after writes)
  load_chunk(xf, rb+9, t,      f0);
  load_chunk(xf, rb+9, t+256,  f1);
  if (t < 128) load_chunk(xf, rb+9, t+512, f2);

  // MFMA row A: tiles at patches {0..15} and {4..19}
  int m = l&15;
  int fb = ((l>>4)*320) + m*16;       // (o-subgroup)*20*16 + p*16
  f32x4 acc0 = (f32x4){0.f,0.f,0.f,0.f}, acc1 = acc0;
  #pragma unroll
  for (int kt=0;kt<8;kt++){
    int off0 = fb + kt*1280;          // pb=0
    int off1 = off0 + 64;             // pb=4
    bf16x8 bh0 = *(const bf16x8*)(smem+off0);
    bf16x8 bl0 = *(const bf16x8*)(smem+10240+off0);
    bf16x8 bh1 = *(const bf16x8*)(smem+off1);
    bf16x8 bl1 = *(const bf16x8*)(smem+10240+off1);
    acc0 = MFMA16(ah[kt], bh0, acc0);
    acc0 = MFMA16(ah[kt], bl0, acc0);
    acc0 = MFMA16(al[kt], bh0, acc0);
    acc1 = MFMA16(ah[kt], bh1, acc1);
    acc1 = MFMA16(ah[kt], bl1, acc1);
    acc1 = MFMA16(al[kt], bh1, acc1);
  }
  // pool row A horizontally into registers (all lanes, uniform shuffles)
  float vA0[4], vA1[4];
  #pragma unroll
  for (int reg=0;reg<4;reg++){
    float v0 = fmaxf(acc0[reg]+bias[reg], 0.f);
    vA0[reg] = fmaxf(v0, __shfl_xor(v0,1));
    float v1 = fmaxf(acc1[reg]+bias[reg], 0.f);
    vA1[reg] = fmaxf(v1, __shfl_xor(v1,1));
  }
  __syncthreads();   // all waves done reading row-A planes

  // convert + write row B
  write_chunk(smem, t,     f0);
  write_chunk(smem, t+256, f1);
  if (t < 128) write_chunk(smem, t+512, f2);
  __syncthreads();

  // MFMA row B
  acc0 = (f32x4){0.f,0.f,0.f,0.f}; acc1 = acc0;
  #pragma unroll
  for (int kt=0;kt<8;kt++){
    int off0 = fb + kt*1280;
    int off1 = off0 + 64;
    bf16x8 bh0 = *(const bf16x8*)(smem+off0);
    bf16x8 bl0 = *(const bf16x8*)(smem+10240+off0);
    bf16x8 bh1 = *(const bf16x8*)(smem+off1);
    bf16x8 bl1 = *(const bf16x8*)(smem+10240+off1);
    acc0 = MFMA16(ah[kt], bh0, acc0);
    acc0 = MFMA16(ah[kt], bl0, acc0);
    acc0 = MFMA16(al[kt], bh0, acc0);
    acc1 = MFMA16(ah[kt], bh1, acc1);
    acc1 = MFMA16(ah[kt], bl1, acc1);
    acc1 = MFMA16(al[kt], bh1, acc1);
  }
  // pool row B + combine with row A — ALL lanes shuffle; store predicated
  size_t ybase = (size_t)fr*6400 + g*10;
  #pragma unroll
  for (int reg=0;reg<4;reg++){
    int co = w*16 + ((l>>4)<<2) + reg;
    float v0 = fmaxf(acc0[reg]+bias[reg], 0.f);
    v0 = fmaxf(v0, __shfl_xor(v0,1));
    float r0 = fmaxf(vA0[reg], v0);
    float v1 = fmaxf(acc1[reg]+bias[reg], 0.f);
    v1 = fmaxf(v1, __shfl_xor(v1,1));
    float r1 = fmaxf(vA1[reg], v1);
    if ((m&1)==0){
      y1[ybase + co*100 + (m>>1)] = r0;
      if (m >= 12)
        y1[ybase + co*100 + ((4+m)>>1)] = r1;
    }
  }
}

// ================= conv2 (5x5 stride 5) + bias + relu + 2x2 maxpool -> y[640][3] =================
__global__ __launch_bounds__(256) void k_conv2(const float* __restrict__ y1,
                                               const float* __restrict__ W2,
                                               const float* __restrict__ b2,
                                               float* __restrict__ y2){
  __shared__ __align__(16) float yl[6400];
  __shared__ __align__(16) float w2s[4800];
  int fr = blockIdx.x, t = threadIdx.x;
  const float4* src = (const float4*)(y1 + (size_t)fr*6400);
  for (int i=t;i<1600;i+=256) async16(((float4*)yl) + i, (const void*)(src + i));
  for (int i=t;i<1200;i+=256) async16(((float4*)w2s) + i, (const void*)(((const float4*)W2) + i));
  __syncthreads();
  if (t < 192){
    int o = t>>4, l16 = t&15;
    int ch = o>>2, pos = o&3;
    int oy = pos>>1, ox = pos&1;
    float s = 0.f;
    for (int i=0;i<100;i++){
      int k = l16 + (i<<4);
      int ci = k/25; int r = k - ci*25; int ky = r/5, kx = r - ky*5;
      s += yl[ci*100 + (5*oy+ky)*10 + 5*ox + kx] * w2s[ch*1600 + k];
    }
    #pragma unroll
    for (int d=1; d<16; d<<=1) s += __shfl_xor(s, d);
    float v = fmaxf(s + b2[ch], 0.f);
    v = fmaxf(v, __shfl_xor(v, 16));
    v = fmaxf(v, __shfl_xor(v, 32));
    if ((t&63)==0) y2[fr*3 + (t>>6)] = v;
  }
}

// ================= fused BN(train)+sort + 3 RNNs (one block per RNN) =================
__global__ __launch_bounds__(512) void k_rnn(const unsigned short* __restrict__ whh_h,
                                             const unsigned short* __restrict__ whh_l,
                                             const float* __restrict__ y2,
                                             const float* __restrict__ gamma,
                                             const float* __restrict__ beta,
                                             const float* __restrict__ Wih,
                                             const float* __restrict__ bih,
                                             const float* __restrict__ bhh,
                                             float* __restrict__ lasts){
  __shared__ __align__(16) char hsm[36864];  // buf0 @0 (hi|lo 8K+8K), buf1 @16384, seqL @32768
  float* yl   = (float*)hsm;                 // [1920] overlaid in buf0 during phase A
  float* af   = (float*)(hsm + 7680);        // [64]
  float* bfv  = (float*)(hsm + 7936);        // [64]
  float* rngL = (float*)(hsm + 8192);        // [10][3]
  int*   perm = (int*)(hsm + 8320);          // [10][3]
  float* tsb  = (float*)(hsm + 8448);        // [10][3][64]
  float* seqL = (float*)(hsm + 32768);       // [64][16]
  int rnn = blockIdx.x;
  int t = threadIdx.x, w = t>>6, l = t&63;

  bf16x8 Bh[2][8], Bl[2][8];                 // wave w owns n-tiles 2w, 2w+1
  #pragma unroll
  for (int q=0;q<2;q++){
    int nt = 2*w + q;
    #pragma unroll
    for (int kt=0;kt<8;kt++){
      size_t fi = (((((size_t)rnn*16 + nt)*8) + kt)*64 + l)*8;
      Bh[q][kt] = *(const bf16x8*)(whh_h + fi);
      Bl[q][kt] = *(const bf16x8*)(whh_l + fi);
    }
  }
  int o0 = (2*w)*16 + (l&15), o1 = o0 + 16;
  float wih0 = Wih[rnn*256 + o0], wih1 = Wih[rnn*256 + o1];
  float bs0 = bih[rnn*256+o0] + bhh[rnn*256+o0];
  float bs1 = bih[rnn*256+o1] + bhh[rnn*256+o1];

  // ---- phase A: BN + sort + seq build ----
  for (int i=t;i<1920;i+=512) yl[i] = y2[i];
  __syncthreads();
  if (t < 64){
    float mu = 0.f;
    for (int b=0;b<10;b++)
      for (int ch=0;ch<3;ch++) mu += yl[(b*64 + t)*3 + ch];
    mu *= (1.f/30.f);
    float v = 0.f;
    for (int b=0;b<10;b++)
      for (int ch=0;ch<3;ch++){ float d = yl[(b*64+t)*3+ch] - mu; v += d*d; }
    v *= (1.f/30.f);
    float rs = rsqrtf(v + 1e-5f);
    float a = gamma[t]*rs;
    af[t] = a; bfv[t] = beta[t] - mu*a;
  }
  __syncthreads();
  if (t < 30){
    int b = t/3, ch = t - b*3;
    float mx = -1e30f, mn = 1e30f;
    for (int f=0; f<64; f++){
      float v = yl[(b*64+f)*3+ch]*af[f] + bfv[f];
      tsb[(b*3+ch)*64 + f] = v;
      mx = fmaxf(mx, v); mn = fminf(mn, v);
    }
    rngL[b*3+ch] = mx - mn;
  }
  __syncthreads();
  if (t < 10){
    #pragma unroll
    for (int ch=0; ch<3; ch++){
      float rc = rngL[t*3+ch];
      int rank = 0;
      #pragma unroll
      for (int c2=0; c2<3; c2++){
        float r2 = rngL[t*3+c2];
        if (r2 < rc || (r2 == rc && c2 < ch)) rank++;   // stable argsort ascending
      }
      perm[t*3+rank] = ch;
    }
  }
  __syncthreads();
  for (int i=t;i<1024;i+=512){
    int step = i>>4, b = i&15;
    float v = 0.f;
    if (b < 10){ int p = perm[b*3 + rnn]; v = tsb[(b*3+p)*64 + step]; }
    seqL[i] = v;
  }
  __syncthreads();

  // ---- phase B: recurrence ----
  float4 z4 = {0.f,0.f,0.f,0.f};
  for (int i=t; i<1024; i+=512) ((float4*)hsm)[i] = z4;   // zero buf0 (h=0)
  __syncthreads();
  int arow = l&15, colb = (l>>4)<<4, sw = (arow&7)<<4;
  int b_base = (l>>4)<<2;
  for (int step=0; step<64; step++){
    char* cur = hsm + ((step&1)<<14);
    char* nxt = hsm + (((step+1)&1)<<14);
    f32x4 p0=(f32x4){0,0,0,0}, q0=p0, r0=p0, p1=p0, q1=p0, r1=p0;
    #pragma unroll
    for (int kt=0; kt<8; kt++){
      int off = ((arow<<9) + (kt<<6) + colb) ^ sw;
      bf16x8 ahv = *(const bf16x8*)(cur + off);
      bf16x8 alv = *(const bf16x8*)(cur + 8192 + off);
      p0 = MFMA16(ahv, Bh[0][kt], p0);
      q0 = MFMA16(ahv, Bl[0][kt], q0);
      r0 = MFMA16(alv, Bh[0][kt], r0);
      p1 = MFMA16(ahv, Bh[1][kt], p1);
      q1 = MFMA16(ahv, Bl[1][kt], q1);
      r1 = MFMA16(alv, Bh[1][kt], r1);
    }
    float4 sx = *(const float4*)(seqL + (step<<4) + b_base);
    float sxa[4] = {sx.x, sx.y, sx.z, sx.w};
    #pragma unroll
    for (int reg=0; reg<4; reg++){
      int b = b_base + reg;
      float a0 = (p0[reg] + q0[reg]) + r0[reg];
      float a1 = (p1[reg] + q1[reg]) + r1[reg];
      float h0 = tanh_fast(a0 + sxa[reg]*wih0 + bs0);
      float h1 = tanh_fast(a1 + sxa[reg]*wih1 + bs1);
      int wsw = (b&7)<<4;
      int off0 = ((b<<9) + (o0<<1)) ^ wsw;
      int off1 = ((b<<9) + (o1<<1)) ^ wsw;
      unsigned int u0 = __float_as_uint(h0);
      unsigned int u1 = __float_as_uint(h1);
      *(unsigned short*)(nxt + off0) = (unsigned short)(u0>>16);
      float l0 = h0 - __uint_as_float(u0 & 0xffff0000u);
      *(unsigned short*)(nxt + 8192 + off0) = (unsigned short)(__float_as_uint(l0)>>16);
      *(unsigned short*)(nxt + off1) = (unsigned short)(u1>>16);
      float l1 = h1 - __uint_as_float(u1 & 0xffff0000u);
      *(unsigned short*)(nxt + 8192 + off1) = (unsigned short)(__float_as_uint(l1)>>16);
      if (step == 63){
        lasts[((size_t)rnn*16 + b)*256 + o0] = h0;
        lasts[((size_t)rnn*16 + b)*256 + o1] = h1;
      }
    }
    __syncthreads();
  }
}

// ================= head: avg over 3 RNNs, @ Wl^T + bl -> out[10][5] =================
__global__ __launch_bounds__(512) void k_head(const float* __restrict__ lasts,
                                              const float* __restrict__ Wl,
                                              const float* __restrict__ bl,
                                              float* __restrict__ out){
  int t = threadIdx.x;
  if (t < 400){
    int oidx = t>>3, l8 = t&7;       // 50 outputs x 8 lanes
    int b = oidx/5, c = oidx - b*5;
    float s = 0.f;
    for (int i=0;i<32;i++){
      int o = (l8<<5) + i;
      float avg = (lasts[(size_t)(0*16+b)*256+o] + lasts[(size_t)(1*16+b)*256+o]
                 + lasts[(size_t)(2*16+b)*256+o]) * (1.f/3.f);
      s += avg * Wl[c*256 + o];
    }
    #pragma unroll
    for (int d=1; d<8; d<<=1) s += __shfl_xor(s, d);
    if (l8 == 0) out[oidx] = s + bl[c];
  }
}

extern "C" void kernel_launch(void* const* d_in, const int* in_sizes, int n_in,
                              void* d_out, int out_size, void* d_ws, size_t ws_size,
                              hipStream_t stream){
  const float* x    = (const float*)d_in[0];
  const float* W1   = (const float*)d_in[1];
  const float* b1   = (const float*)d_in[2];
  const float* W2   = (const float*)d_in[3];
  const float* b2   = (const float*)d_in[4];
  const float* gamma= (const float*)d_in[5];
  const float* beta = (const float*)d_in[6];
  const float* Wih  = (const float*)d_in[7];
  const float* Whh  = (const float*)d_in[8];
  const float* bih  = (const float*)d_in[9];
  const float* bhh  = (const float*)d_in[10];
  const float* Wl   = (const float*)d_in[11];
  const float* bl   = (const float*)d_in[12];
  char* ws = (char*)d_ws;
  unsigned short* w1h  = (unsigned short*)(ws + WS_W1H);
  unsigned short* w1l  = (unsigned short*)(ws + WS_W1L);
  unsigned short* whhh = (unsigned short*)(ws + WS_WHHH);
  unsigned short* whhl = (unsigned short*)(ws + WS_WHHL);
  float* y1   = (float*)(ws + WS_Y1);
  float* y2   = (float*)(ws + WS_Y2);
  float* last = (float*)(ws + WS_LAST);

  hipLaunchKernelGGL(k_prep,  dim3(104),  dim3(256), 0, stream, W1, Whh, w1h, w1l, whhh, whhl);
  hipLaunchKernelGGL(k_conv1, dim3(6400), dim3(256), 0, stream, x, b1, w1h, w1l, y1);
  hipLaunchKernelGGL(k_conv2, dim3(640),  dim3(256), 0, stream, y1, W2, b2, y2);
  hipLaunchKernelGGL(k_rnn,   dim3(3),    dim3(512), 0, stream, whhh, whhl, y2, gamma, beta, Wih, bih, bhh, last);
  hipLaunchKernelGGL(k_head,  dim3(1),    dim3(512), 0, stream, last, Wl, bl, (float*)d_out);
}